// Round 5
// baseline (530.147 us; speedup 1.0000x reference)
//
#include <hip/hip_runtime.h>
#include <hip/hip_bf16.h>
#include <stdint.h>

// CKA loss via algebraic reduction:
//   HSIC_ij = ||Xi^T Xj||_F^2 - <d_i,d_j> - 2N<r_i,r_j> + N^2 t_i t_j
// Heavy part: 21 fp8 MFMA GEMMs [512x4096]x[4096x512], Frobenius-reduced.
//
// R17: ABLATION ROUND. R12-R16 established: gemm pinned at ~41-42 us,
// invariant to waves/CU (8 vs 16), pipeline depth, barrier structure and
// LDS-read volume; only <8 waves/CU hurts. No single pipe accounts for it
// (MFMA 17%, VALU 11%, HBM 14%, LDS-read ~12-19us, staging ~7us).
// Real path: R16 verbatim (passes, 129.5us). Appended: three diagnostic
// kernels that isolate {staging+waits, dsread+MFMA, stats} on the same
// grid/addressing, writing only dead scratch. Their dur_us rows in next
// round's rocprof table identify the binding phase. Costs ~60-90us this
// round by design.

#define NPTS  4096
#define DF    512
#define ML    6
#define NPAIR 21
#define BKB   128                // K-bytes per LDS tile row (= 128 fp8 elems)
#define NDIAGBLK 60              // 6 layers x 10 upper-tri 128-tiles
#define NOFFBLK  240             // 15 pairs x 16 tiles
#define NGEMMBLK (NDIAGBLK + NOFFBLK)
#define NSTATS   96              // 192 stat units, 2 per 512-thread block
#define NTAIL    21              // 21 pairdots
#define TILEB (128 * BKB)        // 16 KB per LDS tile buffer

typedef float  f32x4 __attribute__((ext_vector_type(4)));
typedef int    i32x4v __attribute__((ext_vector_type(4)));
typedef int    i32x8v __attribute__((ext_vector_type(8)));
typedef unsigned char u8;

__constant__ int c_PI[NPAIR] = {0,0,0,0,0,0, 1,1,1,1,1, 2,2,2,2, 3,3,3, 4,4, 5};
__constant__ int c_PJ[NPAIR] = {0,1,2,3,4,5, 1,2,3,4,5, 2,3,4,5, 3,4,5, 4,5, 5};
__constant__ int c_DIAGP[ML]  = {0, 6, 11, 15, 18, 20};     // p for (i,i)
__constant__ int c_OFFP[15]   = {1,2,3,4,5, 7,8,9,10, 12,13,14, 16,17, 19};
__constant__ int c_TM[10] = {0,0,0,0, 1,1,1, 2,2, 3};       // upper-tri 4x4
__constant__ int c_TN[10] = {0,1,2,3, 1,2,3, 2,3, 3};

// ---- workspace layout (bytes) ----
#define OFF_XT8  0u                       // 6*512*4096   = 12582912
#define OFF_SP   12582912u                // 6*64*512*4   = 786432 (col-sum partials)
#define OFF_DVP  13369344u                // 6*8*4096*4   = 786432 (row-sq partials)
#define OFF_F    14155776u                // 21 floats; cnt at +256; tbss at +512
#define OFF_D    (OFF_F + 1024u)          // 98304 (dv, atomic-accumulated)
#define OFF_XS   (OFF_D + 98304u)         // 98304 (xs, atomic-accumulated)
#define OFF_DD   (OFF_XS + 98304u)
#define OFF_RD   (OFF_DD + 256u)
#define OFF_T    (OFF_RD + 256u)
// ---- diagnostic scratch (dead stores only) ----
#define OFF_SCRF (OFF_T + 4096u)          // 600 floats diag outputs
#define OFF_D2   (OFF_SCRF + 4096u)       // 98304 scratch dv
#define OFF_XS2  (OFF_D2 + 98304u)        // 98304 scratch xs
#define OFF_TB2  (OFF_XS2 + 98304u)       // 256 scratch tbss
// total ~14.8 MB

#define UNIT_SCALE 127                    // e8m0: 2^(127-127) = 1.0

__device__ __forceinline__ unsigned short f2fp8x2(float a, float b) {
    return (unsigned short)(__builtin_amdgcn_cvt_pk_fp8_f32(a, b, 0, false) & 0xffff);
}

__device__ __forceinline__ void gl2lds16(const void* g, void* l) {
    __builtin_amdgcn_global_load_lds(
        (__attribute__((address_space(1))) void*)g,
        (__attribute__((address_space(3))) void*)l, 16, 0, 0);
}

// load one 32B MX fragment (k-block = quad*32..+31) from a swizzled LDS row
__device__ __forceinline__ i32x8v frag32(const u8* base, int row, int quad) {
    int sw = row & 7;
    i32x4v lo = *(const i32x4v*)&base[row * BKB + ((2 * quad) ^ sw) * 16];
    i32x4v hi = *(const i32x4v*)&base[row * BKB + ((2 * quad + 1) ^ sw) * 16];
    return __builtin_shufflevector(lo, hi, 0, 1, 2, 3, 4, 5, 6, 7);
}

// stage one 128-row x 128B tile with 8 waves (2 gl2lds16 per thread)
__device__ __forceinline__ void stage128w8(const u8* __restrict__ G, u8* L,
                                           int wave, int rl, int g, int k0) {
#pragma unroll
    for (int is = 0; is < 2; ++is) {
        int rbase = is * 64 + wave * 8;
        int r = rbase + rl;
        int gs = g ^ (r & 7);
        gl2lds16(G + (size_t)r * NPTS + k0 + gs * 16, &L[rbase * BKB]);
    }
}

// shared helper: resolve gemm block -> A,B panels (same for real + diags)
__device__ __forceinline__ void gemm_addr(int b, const u8* __restrict__ Xt8,
                                          const u8** A, const u8** B,
                                          int* p, float* w) {
    if (b < NDIAGBLK) {
        int li = b / 10, tt = b % 10;
        *p = c_DIAGP[li];
        *w = (c_TM[tt] == c_TN[tt]) ? 1.0f : 2.0f;
        *A = Xt8 + ((size_t)(li * DF + c_TM[tt] * 128)) * NPTS;
        *B = Xt8 + ((size_t)(li * DF + c_TN[tt] * 128)) * NPTS;
    } else {
        int b2 = b - NDIAGBLK, op = b2 >> 4, tile = b2 & 15;
        *p = c_OFFP[op];
        *w = 1.0f;
        *A = Xt8 + ((size_t)(c_PI[*p] * DF + (tile & 3) * 128)) * NPTS;
        *B = Xt8 + ((size_t)(c_PJ[*p] * DF + (tile >> 2) * 128)) * NPTS;
    }
}

__device__ __forceinline__ int xcd_swz(int orig) {
    int xcd = orig & 7, idx = orig >> 3;
    const int q = NGEMMBLK >> 3, r = NGEMMBLK & 7;         // 37, 4
    return (xcd < r ? xcd * (q + 1) : r * (q + 1) + (xcd - r) * q) + idx;
}

// ------- K1: transpose + fp32->fp8 + partial stats + zero-init ---------------
__global__ __launch_bounds__(256) void k_transpose(const float* __restrict__ X,
                                                   u8* __restrict__ Xt8,
                                                   float* __restrict__ sp,
                                                   float* __restrict__ dvp,
                                                   float* __restrict__ F,
                                                   unsigned* __restrict__ cnt,
                                                   float* __restrict__ tbss,
                                                   float* __restrict__ dv,
                                                   float* __restrict__ xs) {
    __shared__ float tT[64][67];
    int nt = blockIdx.x, dt = blockIdx.y, l = blockIdx.z;
    int n0 = nt * 64, d0 = dt * 64;
    int t = threadIdx.x, q = t & 15, r = t >> 4;           // q: d-quad, r: n-row
    if (dt == 0) {
        int zb = (l << 6) + nt;                            // 0..383
        if (t < 64)            dv[zb * 64 + t] = 0.f;
        else if (t < 128)      xs[zb * 64 + (t - 64)] = 0.f;
        if (zb == 0) {
            if (t >= 128 && t < 128 + NPAIR) F[t - 128] = 0.f;
            if (t == 155) *cnt = 0u;
            if (t >= 160 && t < 160 + ML) tbss[t - 160] = 0.f;
        }
    }
    const float4* src = (const float4*)(X + ((size_t)l * NPTS + n0) * DF + d0);
#pragma unroll
    for (int p = 0; p < 4; ++p) {
        int rr = r + 16 * p;
        float4 v = src[(size_t)rr * (DF / 4) + q];
        tT[4 * q + 0][rr] = v.x;
        tT[4 * q + 1][rr] = v.y;
        tT[4 * q + 2][rr] = v.z;
        tT[4 * q + 3][rr] = v.w;
    }
    __syncthreads();
    if (t < 64) {                        // column sums over n (d = t)
        float cs = 0.f;
#pragma unroll
        for (int k = 0; k < 64; ++k) {
            int n = (6 * t + k) & 63;    // rotation -> 2-way banks
            cs += tT[t][n];
        }
        sp[((l << 6) + nt) * DF + d0 + t] = cs;
    } else if (t < 128) {                // row sums of squares over d (n = t-64)
        int n = t - 64;
        float rs = 0.f;
#pragma unroll
        for (int d = 0; d < 64; ++d) { float v = tT[d][n]; rs += v * v; }
        dvp[((l << 3) + dt) * NPTS + n0 + n] = rs;
    }
    // write phase: thread -> (dcol = t>>2, 16 n's) packed as uint4 of fp8
    int dcol = t >> 2, nb = (t & 3) * 16;
    uint4 o;
#pragma unroll
    for (int w2 = 0; w2 < 4; ++w2) {
        int j = nb + w2 * 4;
        unsigned lo = f2fp8x2(tT[dcol][j + 0], tT[dcol][j + 1]);
        unsigned hi = f2fp8x2(tT[dcol][j + 2], tT[dcol][j + 3]);
        ((unsigned*)&o)[w2] = lo | (hi << 16);
    }
    *(uint4*)(Xt8 + ((size_t)(l * DF + d0 + dcol)) * NPTS + n0 + nb) = o;
}

// ---------------- K2: MX-fp8 MFMA GEMM + parallel stats blocks ---------------
// (R16 verbatim) 512 threads (8 waves). b < 300: one 128x128 C-tile, full
// K=4096, dbuf, Frobenius -> atomicAdd F[p]. b >= 300: two stat units.
__global__ __launch_bounds__(512, 4) void k_gemm_frob(const u8* __restrict__ Xt8,
                                                      float* __restrict__ F,
                                                      const float* __restrict__ sp,
                                                      const float* __restrict__ dvp,
                                                      float* __restrict__ dv,
                                                      float* __restrict__ xs,
                                                      float* __restrict__ tbss) {
    __shared__ __align__(16) u8 As[2][TILEB];              // 32 KB
    __shared__ __align__(16) u8 Bs[2][TILEB];              // 32 KB

    int orig = blockIdx.x;
    int b = (orig < NGEMMBLK) ? xcd_swz(orig) : orig;
    int t = threadIdx.x, wave = t >> 6, lane = t & 63;
    int rl = lane >> 3, g = lane & 7;          // staging: row-in-8, 16B group
    int row16 = lane & 15, quad = lane >> 4;   // MFMA fragment indices

    if (b < NGEMMBLK) {
        const u8 *A, *B; int p; float w;
        gemm_addr(b, Xt8, &A, &B, &p, &w);

        // 8-wave tiling: wave -> (wr in {0,64}, wc in {0,32,64,96})
        int wr = (wave >> 2) * 64, wc = (wave & 3) * 32;
        f32x4 acc[4][2];
#pragma unroll
        for (int mi = 0; mi < 4; ++mi)
#pragma unroll
            for (int ni = 0; ni < 2; ++ni) acc[mi][ni] = (f32x4)0.0f;

        stage128w8(A, As[0], wave, rl, g, 0);
        stage128w8(B, Bs[0], wave, rl, g, 0);
        int cur = 0;
        const int NIT = NPTS / BKB;                        // 32
        for (int it = 0; it < NIT; ++it) {
            if (it < NIT - 1) {
                int kN = (it + 1) * BKB;
                stage128w8(A, As[cur ^ 1], wave, rl, g, kN);
                stage128w8(B, Bs[cur ^ 1], wave, rl, g, kN);
                asm volatile("s_waitcnt vmcnt(4)" ::: "memory");
            } else {
                asm volatile("s_waitcnt vmcnt(0)" ::: "memory");
            }
            __builtin_amdgcn_s_barrier();
            asm volatile("" ::: "memory");
            i32x8v af[4];
#pragma unroll
            for (int mi = 0; mi < 4; ++mi)
                af[mi] = frag32(As[cur], wr + mi * 16 + row16, quad);
#pragma unroll
            for (int ni = 0; ni < 2; ++ni) {
                i32x8v bf = frag32(Bs[cur], wc + ni * 16 + row16, quad);
#pragma unroll
                for (int mi = 0; mi < 4; ++mi)
                    acc[mi][ni] = __builtin_amdgcn_mfma_scale_f32_16x16x128_f8f6f4(
                        af[mi], bf, acc[mi][ni], 0, 0,
                        0, UNIT_SCALE, 0, UNIT_SCALE);
            }
            asm volatile("s_waitcnt lgkmcnt(0)" ::: "memory");
            __builtin_amdgcn_s_barrier();
            asm volatile("" ::: "memory");
            cur ^= 1;
        }

        float local = 0.f;
#pragma unroll
        for (int mi = 0; mi < 4; ++mi)
#pragma unroll
            for (int ni = 0; ni < 2; ++ni)
#pragma unroll
                for (int e = 0; e < 4; ++e)
                    local += acc[mi][ni][e] * acc[mi][ni][e];
        for (int off = 32; off; off >>= 1) local += __shfl_down(local, off);
        __shared__ float wsum[8];
        if (lane == 0) wsum[wave] = local;
        __syncthreads();
        if (t == 0) {
            float s = 0.f;
#pragma unroll
            for (int k = 0; k < 8; ++k) s += wsum[k];
            atomicAdd(&F[p], w * s);
        }
    } else {
        // ---- stats: two units per block. unit sid -> (l, dc, nc). ----
        int half = t >> 8, tl = t & 255;
        int sid = (b - NGEMMBLK) * 2 + half;               // 0..191
        int l = sid >> 5, rem = sid & 31, dc = rem >> 2, nc = rem & 3;
        int d0 = dc * 64, n0 = nc * 1024;
        float* scratch = (float*)As + half * 384;          // 256 + 64 floats
        float* slp = scratch + 256;

        int dl = tl & 63, part = tl >> 6;
        float a = 0.f;
#pragma unroll 4
        for (int k = 0; k < 16; ++k)
            a += sp[((l << 6) + part * 16 + k) * DF + d0 + dl];
        scratch[tl] = a;
        __syncthreads();
        if (tl < 64)
            slp[tl] = scratch[tl] + scratch[64 + tl] + scratch[128 + tl] + scratch[192 + tl];
        __syncthreads();
        if (nc == 0 && tl == 0) {
            float q2 = 0.f;
#pragma unroll
            for (int d = 0; d < 64; ++d) q2 += slp[d] * slp[d];
            atomicAdd(&tbss[l], q2);
        }
        int n = n0 + tl * 4;
        const u8* xb = Xt8 + (size_t)(l * DF + d0) * NPTS + n;
        float a0 = 0, a1 = 0, a2 = 0, a3 = 0;
#pragma unroll 8
        for (int dd = 0; dd < 64; ++dd) {
            unsigned v = *(const unsigned*)(xb + (size_t)dd * NPTS);
            float sv = slp[dd];
            a0 += sv * __builtin_amdgcn_cvt_f32_fp8(v, 0);
            a1 += sv * __builtin_amdgcn_cvt_f32_fp8(v, 1);
            a2 += sv * __builtin_amdgcn_cvt_f32_fp8(v, 2);
            a3 += sv * __builtin_amdgcn_cvt_f32_fp8(v, 3);
        }
        float* xo = xs + l * NPTS + n;
        atomicAdd(&xo[0], a0); atomicAdd(&xo[1], a1);
        atomicAdd(&xo[2], a2); atomicAdd(&xo[3], a3);
        float4 dp = *(const float4*)(dvp + ((l << 3) + dc) * NPTS + n);
        float* dvo = dv + l * NPTS + n;
        atomicAdd(&dvo[0], dp.x); atomicAdd(&dvo[1], dp.y);
        atomicAdd(&dvo[2], dp.z); atomicAdd(&dvo[3], dp.w);
    }
}

// -------- K3: pairdots (21) + last-block finalize ----------------------------
__global__ __launch_bounds__(256) void k_tail(const float* __restrict__ dv,
                                              const float* __restrict__ xs,
                                              const float* __restrict__ tbss,
                                              float* __restrict__ F,
                                              float* __restrict__ ddot,
                                              float* __restrict__ rdot,
                                              float* __restrict__ tb,
                                              unsigned* __restrict__ cnt,
                                              float* __restrict__ out) {
    __shared__ float4 red[256];
    __shared__ int lastFlag;
    __shared__ float tbv[ML];
    __shared__ double hs[ML][ML];
    __shared__ float cka[ML][ML];

    int b = blockIdx.x, t = threadIdx.x;

    {
        int p = b, i = c_PI[p], j = c_PJ[p];
        const float invN = 1.0f / (float)NPTS;
        float dd = 0.f, rr = 0.f, sd = 0.f;
        for (int n = t; n < NPTS; n += 256) {
            float di = dv[i * NPTS + n], dj = dv[j * NPTS + n];
            float ri = (xs[i * NPTS + n] - di) * invN;
            float rj = (xs[j * NPTS + n] - dj) * invN;
            dd += di * dj;
            rr += ri * rj;
            sd += di;
        }
        red[t] = make_float4(dd, rr, sd, 0.f);
        __syncthreads();
        for (int h = 128; h > 0; h >>= 1) {
            if (t < h) {
                float4 a = red[t], bb = red[t + h];
                red[t] = make_float4(a.x + bb.x, a.y + bb.y, a.z + bb.z, 0.f);
            }
            __syncthreads();
        }
        if (t == 0) {
            atomicExch(&ddot[p], red[0].x);
            atomicExch(&rdot[p], red[0].y);
            if (i == j)
                atomicExch(&tb[i],
                    (tbss[i] - red[0].z) * (1.0f / ((float)NPTS * (float)NPTS)));
        }
    }

    __syncthreads();
    if (t == 0) {
        __threadfence();
        unsigned old = atomicAdd(cnt, 1u);
        lastFlag = (old == NTAIL - 1);
    }
    __syncthreads();
    if (!lastFlag) return;
    __threadfence();
    if (t < ML) tbv[t] = atomicAdd(&tb[t], 0.0f);
    __syncthreads();
    if (t < NPAIR) {
        int i = c_PI[t], j = c_PJ[t];
        double Fv = (double)atomicAdd(&F[t], 0.0f);
        double dd = (double)atomicAdd(&ddot[t], 0.0f);
        double rd = (double)atomicAdd(&rdot[t], 0.0f);
        double v = Fv - dd - 2.0 * (double)NPTS * rd
                 + (double)NPTS * (double)NPTS * (double)tbv[i] * (double)tbv[j];
        hs[i][j] = v; hs[j][i] = v;
    }
    __syncthreads();
    if (t < ML * ML) {
        int i = t / ML, j = t % ML;
        float v;
        if (i == j) v = 1.0f;
        else v = (float)(fabs(hs[i][j]) / sqrt(hs[i][i] * hs[j][j] + 1e-6));
        cka[i][j] = v;
        out[t] = v;
    }
    __syncthreads();
    if (t == 0) {
        float l = 0.f;
        for (int i = 1; i < ML; ++i)
            for (int j = 0; j < i; ++j) l += cka[i][j];   // cka >= 0
        out[ML * ML] = l;
    }
}

// ============ DIAGNOSTICS (dead scratch only; read next round's table) =======

// D1: staging loop only — gl2lds + counted vmcnt + both barriers, no compute.
__global__ __launch_bounds__(512, 4) void k_diag_stage(const u8* __restrict__ Xt8,
                                                       float* __restrict__ scr) {
    __shared__ __align__(16) u8 As[2][TILEB];
    __shared__ __align__(16) u8 Bs[2][TILEB];
    int b = xcd_swz(blockIdx.x);
    int t = threadIdx.x, wave = t >> 6, lane = t & 63;
    int rl = lane >> 3, g = lane & 7;
    const u8 *A, *B; int p; float w;
    gemm_addr(b, Xt8, &A, &B, &p, &w);

    stage128w8(A, As[0], wave, rl, g, 0);
    stage128w8(B, Bs[0], wave, rl, g, 0);
    int cur = 0;
    const int NIT = NPTS / BKB;
    for (int it = 0; it < NIT; ++it) {
        if (it < NIT - 1) {
            int kN = (it + 1) * BKB;
            stage128w8(A, As[cur ^ 1], wave, rl, g, kN);
            stage128w8(B, Bs[cur ^ 1], wave, rl, g, kN);
            asm volatile("s_waitcnt vmcnt(4)" ::: "memory");
        } else {
            asm volatile("s_waitcnt vmcnt(0)" ::: "memory");
        }
        __builtin_amdgcn_s_barrier();
        asm volatile("" ::: "memory");
        // (compute phase elided)
        __builtin_amdgcn_s_barrier();
        asm volatile("" ::: "memory");
        cur ^= 1;
    }
    if (t == 0) scr[b] = (float)As[0][0] + (float)Bs[0][0];
}

// D2: compute loop only — stage both buffers once, then 32 iters of
// frag32 + MFMA + lgkmcnt + both barriers; no staging, no vmcnt in loop.
__global__ __launch_bounds__(512, 4) void k_diag_comp(const u8* __restrict__ Xt8,
                                                      float* __restrict__ scr) {
    __shared__ __align__(16) u8 As[2][TILEB];
    __shared__ __align__(16) u8 Bs[2][TILEB];
    int b = xcd_swz(blockIdx.x);
    int t = threadIdx.x, wave = t >> 6, lane = t & 63;
    int rl = lane >> 3, g = lane & 7;
    int row16 = lane & 15, quad = lane >> 4;
    const u8 *A, *B; int p; float w;
    gemm_addr(b, Xt8, &A, &B, &p, &w);

    int wr = (wave >> 2) * 64, wc = (wave & 3) * 32;
    f32x4 acc[4][2];
#pragma unroll
    for (int mi = 0; mi < 4; ++mi)
#pragma unroll
        for (int ni = 0; ni < 2; ++ni) acc[mi][ni] = (f32x4)0.0f;

    stage128w8(A, As[0], wave, rl, g, 0);
    stage128w8(B, Bs[0], wave, rl, g, 0);
    stage128w8(A, As[1], wave, rl, g, BKB);
    stage128w8(B, Bs[1], wave, rl, g, BKB);
    asm volatile("s_waitcnt vmcnt(0)" ::: "memory");
    __builtin_amdgcn_s_barrier();
    asm volatile("" ::: "memory");

    const int NIT = NPTS / BKB;
    for (int it = 0; it < NIT; ++it) {
        int cur = it & 1;
        i32x8v af[4];
#pragma unroll
        for (int mi = 0; mi < 4; ++mi)
            af[mi] = frag32(As[cur], wr + mi * 16 + row16, quad);
#pragma unroll
        for (int ni = 0; ni < 2; ++ni) {
            i32x8v bf = frag32(Bs[cur], wc + ni * 16 + row16, quad);
#pragma unroll
            for (int mi = 0; mi < 4; ++mi)
                acc[mi][ni] = __builtin_amdgcn_mfma_scale_f32_16x16x128_f8f6f4(
                    af[mi], bf, acc[mi][ni], 0, 0,
                    0, UNIT_SCALE, 0, UNIT_SCALE);
        }
        asm volatile("s_waitcnt lgkmcnt(0)" ::: "memory");
        __builtin_amdgcn_s_barrier();
        asm volatile("" ::: "memory");
        __builtin_amdgcn_s_barrier();
        asm volatile("" ::: "memory");
    }
    float local = 0.f;
#pragma unroll
    for (int mi = 0; mi < 4; ++mi)
#pragma unroll
        for (int ni = 0; ni < 2; ++ni)
#pragma unroll
            for (int e = 0; e < 4; ++e)
                local += acc[mi][ni][e] * acc[mi][ni][e];
    if (lane == 0) scr[304 + (b & 255)] = local;   // dead store, keeps acc live
}

// D3: stats units only (96 blocks x 2 units), atomics into scratch copies.
__global__ __launch_bounds__(512, 4) void k_diag_stats(const u8* __restrict__ Xt8,
                                                       const float* __restrict__ sp,
                                                       const float* __restrict__ dvp,
                                                       float* __restrict__ dv2,
                                                       float* __restrict__ xs2,
                                                       float* __restrict__ tb2) {
    __shared__ float sc[768];
    int b = blockIdx.x, t = threadIdx.x;
    int half = t >> 8, tl = t & 255;
    int sid = b * 2 + half;
    int l = sid >> 5, rem = sid & 31, dc = rem >> 2, nc = rem & 3;
    int d0 = dc * 64, n0 = nc * 1024;
    float* scratch = sc + half * 384;
    float* slp = scratch + 256;

    int dl = tl & 63, part = tl >> 6;
    float a = 0.f;
#pragma unroll 4
    for (int k = 0; k < 16; ++k)
        a += sp[((l << 6) + part * 16 + k) * DF + d0 + dl];
    scratch[tl] = a;
    __syncthreads();
    if (tl < 64)
        slp[tl] = scratch[tl] + scratch[64 + tl] + scratch[128 + tl] + scratch[192 + tl];
    __syncthreads();
    if (nc == 0 && tl == 0) {
        float q2 = 0.f;
#pragma unroll
        for (int d = 0; d < 64; ++d) q2 += slp[d] * slp[d];
        atomicAdd(&tb2[l], q2);
    }
    int n = n0 + tl * 4;
    const u8* xb = Xt8 + (size_t)(l * DF + d0) * NPTS + n;
    float a0 = 0, a1 = 0, a2 = 0, a3 = 0;
#pragma unroll 8
    for (int dd = 0; dd < 64; ++dd) {
        unsigned v = *(const unsigned*)(xb + (size_t)dd * NPTS);
        float sv = slp[dd];
        a0 += sv * __builtin_amdgcn_cvt_f32_fp8(v, 0);
        a1 += sv * __builtin_amdgcn_cvt_f32_fp8(v, 1);
        a2 += sv * __builtin_amdgcn_cvt_f32_fp8(v, 2);
        a3 += sv * __builtin_amdgcn_cvt_f32_fp8(v, 3);
    }
    float* xo = xs2 + l * NPTS + n;
    atomicAdd(&xo[0], a0); atomicAdd(&xo[1], a1);
    atomicAdd(&xo[2], a2); atomicAdd(&xo[3], a3);
    float4 dp = *(const float4*)(dvp + ((l << 3) + dc) * NPTS + n);
    float* dvo = dv2 + l * NPTS + n;
    atomicAdd(&dvo[0], dp.x); atomicAdd(&dvo[1], dp.y);
    atomicAdd(&dvo[2], dp.z); atomicAdd(&dvo[3], dp.w);
}

extern "C" void kernel_launch(void* const* d_in, const int* in_sizes, int n_in,
                              void* d_out, int out_size, void* d_ws, size_t ws_size,
                              hipStream_t stream) {
    (void)in_sizes; (void)n_in; (void)out_size; (void)ws_size;
    const float* X = (const float*)d_in[0];
    float* out = (float*)d_out;
    char* ws = (char*)d_ws;
    u8*    Xt8 = (u8*)(ws + OFF_XT8);
    float* sp  = (float*)(ws + OFF_SP);
    float* dvp = (float*)(ws + OFF_DVP);
    float* F   = (float*)(ws + OFF_F);
    unsigned* cnt = (unsigned*)(ws + OFF_F + 256u);
    float* tbss = (float*)(ws + OFF_F + 512u);
    float* dv  = (float*)(ws + OFF_D);
    float* xs  = (float*)(ws + OFF_XS);
    float* dd  = (float*)(ws + OFF_DD);
    float* rd  = (float*)(ws + OFF_RD);
    float* tb  = (float*)(ws + OFF_T);
    float* scr = (float*)(ws + OFF_SCRF);
    float* dv2 = (float*)(ws + OFF_D2);
    float* xs2 = (float*)(ws + OFF_XS2);
    float* tb2 = (float*)(ws + OFF_TB2);

    hipLaunchKernelGGL(k_transpose, dim3(64, 8, 6), dim3(256), 0, stream,
                       X, Xt8, sp, dvp, F, cnt, tbss, dv, xs);
    hipLaunchKernelGGL(k_gemm_frob, dim3(NGEMMBLK + NSTATS), dim3(512), 0, stream,
                       Xt8, F, sp, dvp, dv, xs, tbss);
    hipLaunchKernelGGL(k_tail, dim3(NTAIL), dim3(256), 0, stream,
                       dv, xs, tbss, F, dd, rd, tb, cnt, out);
    // ---- diagnostics (results unused; timings read from rocprof) ----
    hipLaunchKernelGGL(k_diag_stage, dim3(NGEMMBLK), dim3(512), 0, stream,
                       Xt8, scr);
    hipLaunchKernelGGL(k_diag_comp, dim3(NGEMMBLK), dim3(512), 0, stream,
                       Xt8, scr);
    hipLaunchKernelGGL(k_diag_stats, dim3(NSTATS), dim3(512), 0, stream,
                       Xt8, sp, dvp, dv2, xs2, tb2);
}

// Round 7
// 131.016 us; speedup vs baseline: 4.0464x; 4.0464x over previous
//
#include <hip/hip_runtime.h>
#include <hip/hip_bf16.h>
#include <stdint.h>

// CKA loss via algebraic reduction:
//   HSIC_ij = ||Xi^T Xj||_F^2 - <d_i,d_j> - 2N<r_i,r_j> + N^2 t_i t_j
// Heavy part: 21 fp8 MFMA GEMMs [512x4096]x[4096x512], Frobenius-reduced.
//
// R19 == R18 resubmitted (round-6 bench was an infra failure: "MI355X
// container failed twice"; no kernel verdict). Self-audit found no
// deadlock/OOB path; gemm/tail byte-identical to the R16 kernel that
// passed. Theory unchanged:
// R18: transpose rewrite. R17 ablation: diag_comp was spill-contaminated
// (856MB scratch writes) and discarded; diag_stage ~20-25us (staging alone
// is not the 41us); gemm is dual-ceiling (staging BW || LDS+MFMA) and near
// its structural limit for 128^2 full-K tiles. Cross-round dur arithmetic
// consistently attributes ~35-40us to k_transpose (floor ~10us): 64B-granule
// scattered stores + scalar packing. New transpose: 256n x 64d blocks
// (grid 16x8x6), 4 sub-windows reuse the proven fp32-LDS + pack arithmetic
// bit-identically; packed fp8 staged in a 2nd LDS tile (word-stride 65),
// cooperative store writes 256B-contiguous per d-row. Stats semantics
// unchanged.

#define NPTS  4096
#define DF    512
#define ML    6
#define NPAIR 21
#define BKB   128                // K-bytes per LDS tile row (= 128 fp8 elems)
#define NDIAGBLK 60              // 6 layers x 10 upper-tri 128-tiles
#define NOFFBLK  240             // 15 pairs x 16 tiles
#define NGEMMBLK (NDIAGBLK + NOFFBLK)
#define NSTATS   96              // 192 stat units, 2 per 512-thread block
#define NTAIL    21              // 21 pairdots
#define TILEB (128 * BKB)        // 16 KB per LDS tile buffer

typedef float  f32x4 __attribute__((ext_vector_type(4)));
typedef int    i32x4v __attribute__((ext_vector_type(4)));
typedef int    i32x8v __attribute__((ext_vector_type(8)));
typedef unsigned char u8;

__constant__ int c_PI[NPAIR] = {0,0,0,0,0,0, 1,1,1,1,1, 2,2,2,2, 3,3,3, 4,4, 5};
__constant__ int c_PJ[NPAIR] = {0,1,2,3,4,5, 1,2,3,4,5, 2,3,4,5, 3,4,5, 4,5, 5};
__constant__ int c_DIAGP[ML]  = {0, 6, 11, 15, 18, 20};     // p for (i,i)
__constant__ int c_OFFP[15]   = {1,2,3,4,5, 7,8,9,10, 12,13,14, 16,17, 19};
__constant__ int c_TM[10] = {0,0,0,0, 1,1,1, 2,2, 3};       // upper-tri 4x4
__constant__ int c_TN[10] = {0,1,2,3, 1,2,3, 2,3, 3};

// ---- workspace layout (bytes) ----
#define OFF_XT8  0u                       // 6*512*4096   = 12582912
#define OFF_SP   12582912u                // 6*64*512*4   = 786432 (col-sum partials)
#define OFF_DVP  13369344u                // 6*8*4096*4   = 786432 (row-sq partials)
#define OFF_F    14155776u                // 21 floats; cnt at +256; tbss at +512
#define OFF_D    (OFF_F + 1024u)          // 98304 (dv, atomic-accumulated)
#define OFF_XS   (OFF_D + 98304u)         // 98304 (xs, atomic-accumulated)
#define OFF_DD   (OFF_XS + 98304u)
#define OFF_RD   (OFF_DD + 256u)
#define OFF_T    (OFF_RD + 256u)
// total ~14.5 MB

#define UNIT_SCALE 127                    // e8m0: 2^(127-127) = 1.0

__device__ __forceinline__ unsigned short f2fp8x2(float a, float b) {
    return (unsigned short)(__builtin_amdgcn_cvt_pk_fp8_f32(a, b, 0, false) & 0xffff);
}

__device__ __forceinline__ void gl2lds16(const void* g, void* l) {
    __builtin_amdgcn_global_load_lds(
        (__attribute__((address_space(1))) void*)g,
        (__attribute__((address_space(3))) void*)l, 16, 0, 0);
}

// load one 32B MX fragment (k-block = quad*32..+31) from a swizzled LDS row
__device__ __forceinline__ i32x8v frag32(const u8* base, int row, int quad) {
    int sw = row & 7;
    i32x4v lo = *(const i32x4v*)&base[row * BKB + ((2 * quad) ^ sw) * 16];
    i32x4v hi = *(const i32x4v*)&base[row * BKB + ((2 * quad + 1) ^ sw) * 16];
    return __builtin_shufflevector(lo, hi, 0, 1, 2, 3, 4, 5, 6, 7);
}

// stage one 128-row x 128B tile with 8 waves (2 gl2lds16 per thread)
__device__ __forceinline__ void stage128w8(const u8* __restrict__ G, u8* L,
                                           int wave, int rl, int g, int k0) {
#pragma unroll
    for (int is = 0; is < 2; ++is) {
        int rbase = is * 64 + wave * 8;
        int r = rbase + rl;
        int gs = g ^ (r & 7);
        gl2lds16(G + (size_t)r * NPTS + k0 + gs * 16, &L[rbase * BKB]);
    }
}

__device__ __forceinline__ int xcd_swz(int orig) {
    int xcd = orig & 7, idx = orig >> 3;
    const int q = NGEMMBLK >> 3, r = NGEMMBLK & 7;         // 37, 4
    return (xcd < r ? xcd * (q + 1) : r * (q + 1) + (xcd - r) * q) + idx;
}

// ------- K1: transpose + fp32->fp8 + partial stats + zero-init ---------------
// Block: 256 n x 64 d. Grid (16, 8, 6). Four 64-n sub-windows through the
// proven fp32 LDS tile; packed fp8 staged in out8 (word-stride 65), then a
// cooperative store phase writes 256B-contiguous runs per d-row.
__global__ __launch_bounds__(256) void k_transpose(const float* __restrict__ X,
                                                   u8* __restrict__ Xt8,
                                                   float* __restrict__ sp,
                                                   float* __restrict__ dvp,
                                                   float* __restrict__ F,
                                                   unsigned* __restrict__ cnt,
                                                   float* __restrict__ tbss,
                                                   float* __restrict__ dv,
                                                   float* __restrict__ xs) {
    __shared__ float tT[64][67];          // fp32 window tile (d-major)
    __shared__ unsigned out8[64 * 65];    // packed fp8 out tile, stride 65 words
    int bx = blockIdx.x, dt = blockIdx.y, l = blockIdx.z;
    int n0 = bx * 256, d0 = dt * 64;
    int t = threadIdx.x, q = t & 15, r = t >> 4;           // load: d-quad, n-row

    if (dt == 0) {
        int base = (l << 12) + (bx << 8);                  // l*4096 + bx*256
        dv[base + t] = 0.f;
        xs[base + t] = 0.f;
        if (l == 0 && bx == 0) {
            if (t < NPAIR) F[t] = 0.f;
            if (t == 32) *cnt = 0u;
            if (t >= 64 && t < 64 + ML) tbss[t - 64] = 0.f;
        }
    }

    int dcol = t >> 2, m = t & 3;                          // pack mapping
#pragma unroll
    for (int w = 0; w < 4; ++w) {
        const float4* src =
            (const float4*)(X + ((size_t)l * NPTS + n0 + w * 64) * DF + d0);
#pragma unroll
        for (int p = 0; p < 4; ++p) {
            int rr = r + 16 * p;
            float4 v = src[(size_t)rr * (DF / 4) + q];
            tT[4 * q + 0][rr] = v.x;
            tT[4 * q + 1][rr] = v.y;
            tT[4 * q + 2][rr] = v.z;
            tT[4 * q + 3][rr] = v.w;
        }
        __syncthreads();
        if (t < 64) {                    // column sums over this n-window (d = t)
            float cs = 0.f;
#pragma unroll
            for (int k = 0; k < 64; ++k) {
                int n = (6 * t + k) & 63;                  // rotation -> 2-way banks
                cs += tT[t][n];
            }
            sp[((l << 6) + (bx * 4 + w)) * DF + d0 + t] = cs;
        } else if (t < 128) {            // row sums of squares over d (n = t-64)
            int n = t - 64;
            float rs = 0.f;
#pragma unroll
            for (int d = 0; d < 64; ++d) { float v = tT[d][n]; rs += v * v; }
            dvp[((l << 3) + dt) * NPTS + n0 + w * 64 + n] = rs;
        }
        // pack (dcol, nb = m*16): 16 n's -> 4 words into out8
#pragma unroll
        for (int j2 = 0; j2 < 4; ++j2) {
            int j = m * 16 + j2 * 4;
            unsigned lo = f2fp8x2(tT[dcol][j + 0], tT[dcol][j + 1]);
            unsigned hi = f2fp8x2(tT[dcol][j + 2], tT[dcol][j + 3]);
            out8[dcol * 65 + w * 16 + m * 4 + j2] = lo | (hi << 16);
        }
        __syncthreads();                 // out8[w] done; tT free for next window
    }

    // cooperative store: pass s covers d-rows s*16 + (t>>4); chunk u = t&15.
    // 16 consecutive threads write 256B contiguous of one d-row.
#pragma unroll
    for (int s = 0; s < 4; ++s) {
        int d = s * 16 + (t >> 4), u = t & 15;
        uint4 o;
        o.x = out8[d * 65 + u * 4 + 0];
        o.y = out8[d * 65 + u * 4 + 1];
        o.z = out8[d * 65 + u * 4 + 2];
        o.w = out8[d * 65 + u * 4 + 3];
        *(uint4*)(Xt8 + ((size_t)(l * DF + d0 + d)) * NPTS + n0 + u * 16) = o;
    }
}

// ---------------- K2: MX-fp8 MFMA GEMM + parallel stats blocks ---------------
// (R16 verbatim) 512 threads (8 waves). b < 300: one 128x128 C-tile, full
// K=4096, dbuf, Frobenius -> atomicAdd F[p]. b >= 300: two stat units.
__global__ __launch_bounds__(512, 4) void k_gemm_frob(const u8* __restrict__ Xt8,
                                                      float* __restrict__ F,
                                                      const float* __restrict__ sp,
                                                      const float* __restrict__ dvp,
                                                      float* __restrict__ dv,
                                                      float* __restrict__ xs,
                                                      float* __restrict__ tbss) {
    __shared__ __align__(16) u8 As[2][TILEB];              // 32 KB
    __shared__ __align__(16) u8 Bs[2][TILEB];              // 32 KB

    int orig = blockIdx.x;
    int b = (orig < NGEMMBLK) ? xcd_swz(orig) : orig;
    int t = threadIdx.x, wave = t >> 6, lane = t & 63;
    int rl = lane >> 3, g = lane & 7;          // staging: row-in-8, 16B group
    int row16 = lane & 15, quad = lane >> 4;   // MFMA fragment indices

    if (b < NGEMMBLK) {
        const u8 *A, *B;
        int p;
        float w = 1.0f;
        if (b < NDIAGBLK) {
            int li = b / 10, tt = b % 10;
            p = c_DIAGP[li];
            w = (c_TM[tt] == c_TN[tt]) ? 1.0f : 2.0f;
            A = Xt8 + ((size_t)(li * DF + c_TM[tt] * 128)) * NPTS;
            B = Xt8 + ((size_t)(li * DF + c_TN[tt] * 128)) * NPTS;
        } else {
            int b2 = b - NDIAGBLK, op = b2 >> 4, tile = b2 & 15;
            p = c_OFFP[op];
            A = Xt8 + ((size_t)(c_PI[p] * DF + (tile & 3) * 128)) * NPTS;
            B = Xt8 + ((size_t)(c_PJ[p] * DF + (tile >> 2) * 128)) * NPTS;
        }

        // 8-wave tiling: wave -> (wr in {0,64}, wc in {0,32,64,96})
        int wr = (wave >> 2) * 64, wc = (wave & 3) * 32;
        f32x4 acc[4][2];
#pragma unroll
        for (int mi = 0; mi < 4; ++mi)
#pragma unroll
            for (int ni = 0; ni < 2; ++ni) acc[mi][ni] = (f32x4)0.0f;

        stage128w8(A, As[0], wave, rl, g, 0);
        stage128w8(B, Bs[0], wave, rl, g, 0);
        int cur = 0;
        const int NIT = NPTS / BKB;                        // 32
        for (int it = 0; it < NIT; ++it) {
            if (it < NIT - 1) {
                int kN = (it + 1) * BKB;
                stage128w8(A, As[cur ^ 1], wave, rl, g, kN);
                stage128w8(B, Bs[cur ^ 1], wave, rl, g, kN);
                asm volatile("s_waitcnt vmcnt(4)" ::: "memory");
            } else {
                asm volatile("s_waitcnt vmcnt(0)" ::: "memory");
            }
            __builtin_amdgcn_s_barrier();
            asm volatile("" ::: "memory");
            i32x8v af[4];
#pragma unroll
            for (int mi = 0; mi < 4; ++mi)
                af[mi] = frag32(As[cur], wr + mi * 16 + row16, quad);
#pragma unroll
            for (int ni = 0; ni < 2; ++ni) {
                i32x8v bf = frag32(Bs[cur], wc + ni * 16 + row16, quad);
#pragma unroll
                for (int mi = 0; mi < 4; ++mi)
                    acc[mi][ni] = __builtin_amdgcn_mfma_scale_f32_16x16x128_f8f6f4(
                        af[mi], bf, acc[mi][ni], 0, 0,
                        0, UNIT_SCALE, 0, UNIT_SCALE);
            }
            asm volatile("s_waitcnt lgkmcnt(0)" ::: "memory");
            __builtin_amdgcn_s_barrier();
            asm volatile("" ::: "memory");
            cur ^= 1;
        }

        float local = 0.f;
#pragma unroll
        for (int mi = 0; mi < 4; ++mi)
#pragma unroll
            for (int ni = 0; ni < 2; ++ni)
#pragma unroll
                for (int e = 0; e < 4; ++e)
                    local += acc[mi][ni][e] * acc[mi][ni][e];
        for (int off = 32; off; off >>= 1) local += __shfl_down(local, off);
        __shared__ float wsum[8];
        if (lane == 0) wsum[wave] = local;
        __syncthreads();
        if (t == 0) {
            float s = 0.f;
#pragma unroll
            for (int k = 0; k < 8; ++k) s += wsum[k];
            atomicAdd(&F[p], w * s);
        }
    } else {
        // ---- stats: two units per block. unit sid -> (l, dc, nc). ----
        int half = t >> 8, tl = t & 255;
        int sid = (b - NGEMMBLK) * 2 + half;               // 0..191
        int l = sid >> 5, rem = sid & 31, dc = rem >> 2, nc = rem & 3;
        int d0 = dc * 64, n0 = nc * 1024;
        float* scratch = (float*)As + half * 384;          // 256 + 64 floats
        float* slp = scratch + 256;

        int dl = tl & 63, part = tl >> 6;
        float a = 0.f;
#pragma unroll 4
        for (int k = 0; k < 16; ++k)
            a += sp[((l << 6) + part * 16 + k) * DF + d0 + dl];
        scratch[tl] = a;
        __syncthreads();
        if (tl < 64)
            slp[tl] = scratch[tl] + scratch[64 + tl] + scratch[128 + tl] + scratch[192 + tl];
        __syncthreads();
        if (nc == 0 && tl == 0) {
            float q2 = 0.f;
#pragma unroll
            for (int d = 0; d < 64; ++d) q2 += slp[d] * slp[d];
            atomicAdd(&tbss[l], q2);
        }
        int n = n0 + tl * 4;
        const u8* xb = Xt8 + (size_t)(l * DF + d0) * NPTS + n;
        float a0 = 0, a1 = 0, a2 = 0, a3 = 0;
#pragma unroll 8
        for (int dd = 0; dd < 64; ++dd) {
            unsigned v = *(const unsigned*)(xb + (size_t)dd * NPTS);
            float sv = slp[dd];
            a0 += sv * __builtin_amdgcn_cvt_f32_fp8(v, 0);
            a1 += sv * __builtin_amdgcn_cvt_f32_fp8(v, 1);
            a2 += sv * __builtin_amdgcn_cvt_f32_fp8(v, 2);
            a3 += sv * __builtin_amdgcn_cvt_f32_fp8(v, 3);
        }
        float* xo = xs + l * NPTS + n;
        atomicAdd(&xo[0], a0); atomicAdd(&xo[1], a1);
        atomicAdd(&xo[2], a2); atomicAdd(&xo[3], a3);
        float4 dp = *(const float4*)(dvp + ((l << 3) + dc) * NPTS + n);
        float* dvo = dv + l * NPTS + n;
        atomicAdd(&dvo[0], dp.x); atomicAdd(&dvo[1], dp.y);
        atomicAdd(&dvo[2], dp.z); atomicAdd(&dvo[3], dp.w);
    }
}

// -------- K3: pairdots (21) + last-block finalize ----------------------------
__global__ __launch_bounds__(256) void k_tail(const float* __restrict__ dv,
                                              const float* __restrict__ xs,
                                              const float* __restrict__ tbss,
                                              float* __restrict__ F,
                                              float* __restrict__ ddot,
                                              float* __restrict__ rdot,
                                              float* __restrict__ tb,
                                              unsigned* __restrict__ cnt,
                                              float* __restrict__ out) {
    __shared__ float4 red[256];
    __shared__ int lastFlag;
    __shared__ float tbv[ML];
    __shared__ double hs[ML][ML];
    __shared__ float cka[ML][ML];

    int b = blockIdx.x, t = threadIdx.x;

    {
        int p = b, i = c_PI[p], j = c_PJ[p];
        const float invN = 1.0f / (float)NPTS;
        float dd = 0.f, rr = 0.f, sd = 0.f;
        for (int n = t; n < NPTS; n += 256) {
            float di = dv[i * NPTS + n], dj = dv[j * NPTS + n];
            float ri = (xs[i * NPTS + n] - di) * invN;
            float rj = (xs[j * NPTS + n] - dj) * invN;
            dd += di * dj;
            rr += ri * rj;
            sd += di;
        }
        red[t] = make_float4(dd, rr, sd, 0.f);
        __syncthreads();
        for (int h = 128; h > 0; h >>= 1) {
            if (t < h) {
                float4 a = red[t], bb = red[t + h];
                red[t] = make_float4(a.x + bb.x, a.y + bb.y, a.z + bb.z, 0.f);
            }
            __syncthreads();
        }
        if (t == 0) {
            atomicExch(&ddot[p], red[0].x);
            atomicExch(&rdot[p], red[0].y);
            if (i == j)
                atomicExch(&tb[i],
                    (tbss[i] - red[0].z) * (1.0f / ((float)NPTS * (float)NPTS)));
        }
    }

    __syncthreads();
    if (t == 0) {
        __threadfence();
        unsigned old = atomicAdd(cnt, 1u);
        lastFlag = (old == NTAIL - 1);
    }
    __syncthreads();
    if (!lastFlag) return;
    __threadfence();
    if (t < ML) tbv[t] = atomicAdd(&tb[t], 0.0f);
    __syncthreads();
    if (t < NPAIR) {
        int i = c_PI[t], j = c_PJ[t];
        double Fv = (double)atomicAdd(&F[t], 0.0f);
        double dd = (double)atomicAdd(&ddot[t], 0.0f);
        double rd = (double)atomicAdd(&rdot[t], 0.0f);
        double v = Fv - dd - 2.0 * (double)NPTS * rd
                 + (double)NPTS * (double)NPTS * (double)tbv[i] * (double)tbv[j];
        hs[i][j] = v; hs[j][i] = v;
    }
    __syncthreads();
    if (t < ML * ML) {
        int i = t / ML, j = t % ML;
        float v;
        if (i == j) v = 1.0f;
        else v = (float)(fabs(hs[i][j]) / sqrt(hs[i][i] * hs[j][j] + 1e-6));
        cka[i][j] = v;
        out[t] = v;
    }
    __syncthreads();
    if (t == 0) {
        float l = 0.f;
        for (int i = 1; i < ML; ++i)
            for (int j = 0; j < i; ++j) l += cka[i][j];   // cka >= 0
        out[ML * ML] = l;
    }
}

extern "C" void kernel_launch(void* const* d_in, const int* in_sizes, int n_in,
                              void* d_out, int out_size, void* d_ws, size_t ws_size,
                              hipStream_t stream) {
    (void)in_sizes; (void)n_in; (void)out_size; (void)ws_size;
    const float* X = (const float*)d_in[0];
    float* out = (float*)d_out;
    char* ws = (char*)d_ws;
    u8*    Xt8 = (u8*)(ws + OFF_XT8);
    float* sp  = (float*)(ws + OFF_SP);
    float* dvp = (float*)(ws + OFF_DVP);
    float* F   = (float*)(ws + OFF_F);
    unsigned* cnt = (unsigned*)(ws + OFF_F + 256u);
    float* tbss = (float*)(ws + OFF_F + 512u);
    float* dv  = (float*)(ws + OFF_D);
    float* xs  = (float*)(ws + OFF_XS);
    float* dd  = (float*)(ws + OFF_DD);
    float* rd  = (float*)(ws + OFF_RD);
    float* tb  = (float*)(ws + OFF_T);

    hipLaunchKernelGGL(k_transpose, dim3(16, 8, 6), dim3(256), 0, stream,
                       X, Xt8, sp, dvp, F, cnt, tbss, dv, xs);
    hipLaunchKernelGGL(k_gemm_frob, dim3(NGEMMBLK + NSTATS), dim3(512), 0, stream,
                       Xt8, F, sp, dvp, dv, xs, tbss);
    hipLaunchKernelGGL(k_tail, dim3(NTAIL), dim3(256), 0, stream,
                       dv, xs, tbss, F, dd, rd, tb, cnt, out);
}

// Round 8
// 127.234 us; speedup vs baseline: 4.1667x; 1.0297x over previous
//
#include <hip/hip_runtime.h>
#include <hip/hip_bf16.h>
#include <stdint.h>

// CKA loss via algebraic reduction:
//   HSIC_ij = ||Xi^T Xj||_F^2 - <d_i,d_j> - 2N<r_i,r_j> + N^2 t_i t_j
// Heavy part: 21 fp8 MFMA GEMMs [512x4096]x[4096x512], Frobenius-reduced.
//
// R20 == R12 (session-best, 127.854 us, absmax 4.2e-4) resubmitted.
// Session conclusion after R13-R19: total = ~83us harness fill/overhead
// (fillBufferAligned at 81% HBM peak, uncontrollable) + gemm 41-44us +
// ~5us rest. The gemm is a lockstep-latency plateau: invariant across 6
// structural variants (barrier structure, pipeline depth 1-3, counted
// vmcnt, LDS-read volume 1.5x A/B, 8 vs 16 waves/CU, block granularity);
// only <8 waves/CU regresses (R15: 4 waves -> +75%). No pipe near ceiling
// (MFMA 17%, LDS ~35%, L2 ~20%, HBM 14%); 8-phase restructure needs 256^2
// tiles -> only 78 blocks at this shape -> starves CUs. Locking the best
// measured configuration.
//
// R12: gemm uses MX-scaled fp8 (mfma_scale_f32_16x16x128_f8f6f4, unit
// e8m0 scales = 127): 2x MFMA rate, 32B/lane fragments -> pure
// ds_read_b128. With uniform scales any A/B-shared k-permutation cancels
// in the dot product and C/D layout is Frobenius-invariant.

#define NPTS  4096
#define DF    512
#define ML    6
#define NPAIR 21
#define BKB   128                // K-bytes per LDS tile row (= 128 fp8 elems)
#define KCHUNK_O 512             // off-diag split-K=8 -> 4 iters
#define KCHUNK_D 1024            // diag split-K=4 -> 8 iters
#define NDIAGBLK 240             // 6 layers x 10 unique tiles x 4 z
#define NOFFBLK  960             // 15 pairs x 8 tiles x 8 z
#define NGEMMBLK (NDIAGBLK + NOFFBLK)
#define NSTATS   192             // 6 layers x 4 n-chunks x 8 d-chunks
#define NTAIL    81              // 60 diagred + 21 pairdots

typedef float  f32x4 __attribute__((ext_vector_type(4)));
typedef int    i32x4v __attribute__((ext_vector_type(4)));
typedef int    i32x8v __attribute__((ext_vector_type(8)));
typedef unsigned char u8;

__constant__ int c_PI[NPAIR] = {0,0,0,0,0,0, 1,1,1,1,1, 2,2,2,2, 3,3,3, 4,4, 5};
__constant__ int c_PJ[NPAIR] = {0,1,2,3,4,5, 1,2,3,4,5, 2,3,4,5, 3,4,5, 4,5, 5};
__constant__ int c_DIAGP[ML]  = {0, 6, 11, 15, 18, 20};     // p for (i,i)
__constant__ int c_OFFP[15]   = {1,2,3,4,5, 7,8,9,10, 12,13,14, 16,17, 19};
__constant__ int c_TM[10] = {0,0,0,0, 1,1,1, 2,2, 3};       // upper-tri 4x4
__constant__ int c_TN[10] = {0,1,2,3, 1,2,3, 2,3, 3};

// ---- workspace layout (bytes) ----
#define OFF_XT8  0u                       // 6*512*4096   = 12582912
#define OFF_CP   12582912u                // 60*4*64KB    = 15728640
#define OFF_SP   28311552u                // 6*64*512*4   = 786432 (col-sum partials)
#define OFF_DVP  29097984u                // 6*8*4096*4   = 786432 (row-sq partials)
#define OFF_F    29884416u                // 21 floats; cnt at +256; tbss at +512
#define OFF_D    (OFF_F + 1024u)          // 98304 (dv, atomic-accumulated)
#define OFF_XS   (OFF_D + 98304u)         // 98304 (xs, atomic-accumulated)
#define OFF_DD   (OFF_XS + 98304u)
#define OFF_RD   (OFF_DD + 256u)
#define OFF_T    (OFF_RD + 256u)
// total ~30.1 MB

#define UNIT_SCALE 127                    // e8m0: 2^(127-127) = 1.0

__device__ __forceinline__ unsigned short f2fp8x2(float a, float b) {
    return (unsigned short)(__builtin_amdgcn_cvt_pk_fp8_f32(a, b, 0, false) & 0xffff);
}

__device__ __forceinline__ void gl2lds16(const void* g, void* l) {
    __builtin_amdgcn_global_load_lds(
        (__attribute__((address_space(1))) void*)g,
        (__attribute__((address_space(3))) void*)l, 16, 0, 0);
}

// load one 32B MX fragment (k-block = quad*32..+31) from a swizzled LDS row
__device__ __forceinline__ i32x8v frag32(const u8* base, int row, int quad) {
    int sw = row & 7;
    i32x4v lo = *(const i32x4v*)&base[row * BKB + ((2 * quad) ^ sw) * 16];
    i32x4v hi = *(const i32x4v*)&base[row * BKB + ((2 * quad + 1) ^ sw) * 16];
    return __builtin_shufflevector(lo, hi, 0, 1, 2, 3, 4, 5, 6, 7);
}

// ------- K1: transpose + fp32->fp8 + partial stats + zero-init ---------------
__global__ __launch_bounds__(256) void k_transpose(const float* __restrict__ X,
                                                   u8* __restrict__ Xt8,
                                                   float* __restrict__ sp,
                                                   float* __restrict__ dvp,
                                                   float* __restrict__ F,
                                                   unsigned* __restrict__ cnt,
                                                   float* __restrict__ tbss,
                                                   float* __restrict__ dv,
                                                   float* __restrict__ xs) {
    __shared__ float tT[64][67];
    int nt = blockIdx.x, dt = blockIdx.y, l = blockIdx.z;
    int n0 = nt * 64, d0 = dt * 64;
    int t = threadIdx.x, q = t & 15, r = t >> 4;           // q: d-quad, r: n-row
    if (dt == 0) {
        int zb = (l << 6) + nt;                            // 0..383
        if (t < 64)            dv[zb * 64 + t] = 0.f;
        else if (t < 128)      xs[zb * 64 + (t - 64)] = 0.f;
        if (zb == 0) {
            if (t >= 128 && t < 128 + NPAIR) F[t - 128] = 0.f;
            if (t == 155) *cnt = 0u;
            if (t >= 160 && t < 160 + ML) tbss[t - 160] = 0.f;
        }
    }
    const float4* src = (const float4*)(X + ((size_t)l * NPTS + n0) * DF + d0);
#pragma unroll
    for (int p = 0; p < 4; ++p) {
        int rr = r + 16 * p;
        float4 v = src[(size_t)rr * (DF / 4) + q];
        tT[4 * q + 0][rr] = v.x;
        tT[4 * q + 1][rr] = v.y;
        tT[4 * q + 2][rr] = v.z;
        tT[4 * q + 3][rr] = v.w;
    }
    __syncthreads();
    if (t < 64) {                        // column sums over n (d = t)
        float cs = 0.f;
#pragma unroll
        for (int k = 0; k < 64; ++k) {
            int n = (6 * t + k) & 63;    // rotation -> 2-way banks
            cs += tT[t][n];
        }
        sp[((l << 6) + nt) * DF + d0 + t] = cs;
    } else if (t < 128) {                // row sums of squares over d (n = t-64)
        int n = t - 64;
        float rs = 0.f;
#pragma unroll
        for (int d = 0; d < 64; ++d) { float v = tT[d][n]; rs += v * v; }
        dvp[((l << 3) + dt) * NPTS + n0 + n] = rs;
    }
    // write phase: thread -> (dcol = t>>2, 16 n's) packed as uint4 of fp8
    int dcol = t >> 2, nb = (t & 3) * 16;
    uint4 o;
#pragma unroll
    for (int w2 = 0; w2 < 4; ++w2) {
        int j = nb + w2 * 4;
        unsigned lo = f2fp8x2(tT[dcol][j + 0], tT[dcol][j + 1]);
        unsigned hi = f2fp8x2(tT[dcol][j + 2], tT[dcol][j + 3]);
        ((unsigned*)&o)[w2] = lo | (hi << 16);
    }
    *(uint4*)(Xt8 + ((size_t)(l * DF + d0 + dcol)) * NPTS + n0 + nb) = o;
}

// ---------------- K2: MX-fp8 MFMA GEMM + parallel stats blocks ---------------
// b < 240: diag pair, split-K=4, 128x128 tile, partial C -> CP (exact later).
// b < 1200: off-diag pair, split-K=8, 128x256 tile, Frobenius -> atomic F.
// b >= 1200: stats (l, n-chunk, d-chunk): atomicAdd into xs/dv; tbss.
__global__ __launch_bounds__(256, 2) void k_gemm_frob(const u8* __restrict__ Xt8,
                                                      float* __restrict__ CP,
                                                      float* __restrict__ F,
                                                      const float* __restrict__ sp,
                                                      const float* __restrict__ dvp,
                                                      float* __restrict__ dv,
                                                      float* __restrict__ xs,
                                                      float* __restrict__ tbss) {
    // single shared allocation for ALL branches (R6 lesson)
    __shared__ __align__(16) u8 As[128 * BKB];             // 16 KB
    __shared__ __align__(16) u8 Bs[256 * BKB];             // 32 KB

    int b = blockIdx.x;
    int t = threadIdx.x, wave = t >> 6, lane = t & 63;
    int rl = lane >> 3, g = lane & 7;          // staging: row-in-8, 16B group
    int row16 = lane & 15, quad = lane >> 4;   // MFMA fragment indices

    if (b < NDIAGBLK) {
        // ---- diag: li, tile tt (10 unique), z in 0..3; 8 iters ----
        int li = b / 40, rem = b % 40, tt = rem >> 2, z = rem & 3;
        int mt = c_TM[tt], nt = c_TN[tt];
        const u8* A = Xt8 + ((size_t)(li * DF + mt * 128)) * NPTS;
        const u8* B = Xt8 + ((size_t)(li * DF + nt * 128)) * NPTS;
        int kLo = z * KCHUNK_D, kHi = kLo + KCHUNK_D;

        int wr = (wave >> 1) * 64, wc = (wave & 1) * 64;
        f32x4 acc[4][4];
#pragma unroll
        for (int mi = 0; mi < 4; ++mi)
#pragma unroll
            for (int ni = 0; ni < 4; ++ni) acc[mi][ni] = (f32x4)0.0f;

        for (int k0 = kLo; k0 < kHi; k0 += BKB) {
            __syncthreads();
#pragma unroll
            for (int is = 0; is < 4; ++is) {               // A,B: 128 rows each
                int rbase = is * 32 + wave * 8;
                int r = rbase + rl;
                int gs = g ^ (r & 7);
                gl2lds16(A + (size_t)r * NPTS + k0 + gs * 16, &As[rbase * BKB]);
                gl2lds16(B + (size_t)r * NPTS + k0 + gs * 16, &Bs[rbase * BKB]);
            }
            __syncthreads();
            i32x8v af[4];
#pragma unroll
            for (int mi = 0; mi < 4; ++mi)
                af[mi] = frag32(As, wr + mi * 16 + row16, quad);
#pragma unroll
            for (int ni = 0; ni < 4; ++ni) {
                i32x8v bf = frag32(Bs, wc + ni * 16 + row16, quad);
#pragma unroll
                for (int mi = 0; mi < 4; ++mi)
                    acc[mi][ni] = __builtin_amdgcn_mfma_scale_f32_16x16x128_f8f6f4(
                        af[mi], bf, acc[mi][ni], 0, 0,
                        0, UNIT_SCALE, 0, UNIT_SCALE);
            }
        }
        // write partial C tile (lane layout identical across z -> sum aligns)
        float* cp = CP + (((size_t)(li * 10 + tt) * 4 + z) * 16384) + wave * 4096;
#pragma unroll
        for (int mi = 0; mi < 4; ++mi)
#pragma unroll
            for (int ni = 0; ni < 4; ++ni)
#pragma unroll
                for (int e = 0; e < 4; ++e)
                    cp[(mi * 4 + ni) * 256 + e * 64 + lane] = acc[mi][ni][e];
    } else if (b < NGEMMBLK) {
        // ---- off-diag: split-K=8, 128x256 tile; 4 iters ----
        int b2 = b - NDIAGBLK;
        int op = b2 >> 6, rem = b2 & 63;
        int tile = rem >> 3, z = rem & 7;
        int pp = c_OFFP[op];
        const u8* A = Xt8 + ((size_t)(c_PI[pp] * DF + (tile & 3) * 128)) * NPTS;
        const u8* B = Xt8 + ((size_t)(c_PJ[pp] * DF + (tile >> 2) * 256)) * NPTS;
        int kLo = z * KCHUNK_O, kHi = kLo + KCHUNK_O;

        int wr = (wave >> 1) * 64, wc = (wave & 1) * 128;
        f32x4 acc[4][8];
#pragma unroll
        for (int mi = 0; mi < 4; ++mi)
#pragma unroll
            for (int ni = 0; ni < 8; ++ni) acc[mi][ni] = (f32x4)0.0f;

        for (int k0 = kLo; k0 < kHi; k0 += BKB) {
            __syncthreads();
#pragma unroll
            for (int is = 0; is < 4; ++is) {               // A: 128 rows
                int rbase = is * 32 + wave * 8;
                int r = rbase + rl;
                int gs = g ^ (r & 7);
                gl2lds16(A + (size_t)r * NPTS + k0 + gs * 16, &As[rbase * BKB]);
            }
#pragma unroll
            for (int is = 0; is < 8; ++is) {               // B: 256 rows
                int rbase = is * 32 + wave * 8;
                int r = rbase + rl;
                int gs = g ^ (r & 7);
                gl2lds16(B + (size_t)r * NPTS + k0 + gs * 16, &Bs[rbase * BKB]);
            }
            __syncthreads();
            i32x8v af[4];
#pragma unroll
            for (int mi = 0; mi < 4; ++mi)
                af[mi] = frag32(As, wr + mi * 16 + row16, quad);
#pragma unroll
            for (int ni = 0; ni < 8; ++ni) {
                i32x8v bf = frag32(Bs, wc + ni * 16 + row16, quad);
#pragma unroll
                for (int mi = 0; mi < 4; ++mi)
                    acc[mi][ni] = __builtin_amdgcn_mfma_scale_f32_16x16x128_f8f6f4(
                        af[mi], bf, acc[mi][ni], 0, 0,
                        0, UNIT_SCALE, 0, UNIT_SCALE);
            }
        }
        float local = 0.f;
#pragma unroll
        for (int mi = 0; mi < 4; ++mi)
#pragma unroll
            for (int ni = 0; ni < 8; ++ni)
#pragma unroll
                for (int e = 0; e < 4; ++e)
                    local += acc[mi][ni][e] * acc[mi][ni][e];
        for (int off = 32; off; off >>= 1) local += __shfl_down(local, off);
        __shared__ float wsum[4];
        if (lane == 0) wsum[wave] = local;
        __syncthreads();
        if (t == 0) atomicAdd(&F[pp], wsum[0] + wsum[1] + wsum[2] + wsum[3]);
    } else {
        // ---- stats: sid -> (l, dc, nc). 64 loads/thread. ----
        int sid = b - NGEMMBLK;
        int l = sid >> 5, rem = sid & 31, dc = rem >> 2, nc = rem & 3;
        int d0 = dc * 64, n0 = nc * 1024;
        float* scratch = (float*)As;                       // 256 floats
        float* slp = (float*)As + 256;                     // 64 floats

        // reduce sp -> s values for this 64-d chunk (into LDS)
        int dl = t & 63, part = t >> 6;
        float a = 0.f;
#pragma unroll 4
        for (int k = 0; k < 16; ++k)
            a += sp[((l << 6) + part * 16 + k) * DF + d0 + dl];
        scratch[t] = a;
        __syncthreads();
        if (t < 64)
            slp[t] = scratch[t] + scratch[64 + t] + scratch[128 + t] + scratch[192 + t];
        __syncthreads();
        if (nc == 0 && t == 0) {                           // sum s^2 chunk
            float q2 = 0.f;
#pragma unroll
            for (int d = 0; d < 64; ++d) q2 += slp[d] * slp[d];
            atomicAdd(&tbss[l], q2);
        }
        // xs partial: 64 strided loads, 4 n's per thread
        int n = n0 + t * 4;
        const u8* xb = Xt8 + (size_t)(l * DF + d0) * NPTS + n;
        float a0 = 0, a1 = 0, a2 = 0, a3 = 0;
#pragma unroll 8
        for (int dd = 0; dd < 64; ++dd) {
            unsigned v = *(const unsigned*)(xb + (size_t)dd * NPTS);
            float sv = slp[dd];
            a0 += sv * __builtin_amdgcn_cvt_f32_fp8(v, 0);
            a1 += sv * __builtin_amdgcn_cvt_f32_fp8(v, 1);
            a2 += sv * __builtin_amdgcn_cvt_f32_fp8(v, 2);
            a3 += sv * __builtin_amdgcn_cvt_f32_fp8(v, 3);
        }
        float* xo = xs + l * NPTS + n;
        atomicAdd(&xo[0], a0); atomicAdd(&xo[1], a1);
        atomicAdd(&xo[2], a2); atomicAdd(&xo[3], a3);
        // dv partial: this block owns dvp chunk dc for its n's
        float4 dp = *(const float4*)(dvp + ((l << 3) + dc) * NPTS + n);
        float* dvo = dv + l * NPTS + n;
        atomicAdd(&dvo[0], dp.x); atomicAdd(&dvo[1], dp.y);
        atomicAdd(&dvo[2], dp.z); atomicAdd(&dvo[3], dp.w);
    }
}

// -------- K3: diagred (60) + pairdots (21) + last-block finalize -------------
__global__ __launch_bounds__(256) void k_tail(const float* __restrict__ CP,
                                              const float* __restrict__ dv,
                                              const float* __restrict__ xs,
                                              const float* __restrict__ tbss,
                                              float* __restrict__ F,
                                              float* __restrict__ ddot,
                                              float* __restrict__ rdot,
                                              float* __restrict__ tb,
                                              unsigned* __restrict__ cnt,
                                              float* __restrict__ out) {
    __shared__ float wsum[4];
    __shared__ float4 red[256];
    __shared__ int lastFlag;
    __shared__ float tbv[ML];
    __shared__ double hs[ML][ML];
    __shared__ float cka[ML][ML];

    int b = blockIdx.x, t = threadIdx.x;

    if (b < 60) {
        // ---- diag reduce: F[ii] += w * sum((sum_z CP_z)^2) ----
        int li = b / 10, tt = b % 10;
        const float* base = CP + (size_t)b * 4 * 16384;
        float a = 0.f;
#pragma unroll 4
        for (int c = 0; c < 64; ++c) {
            int idx = c * 256 + t;
            float v = base[idx] + base[16384 + idx]
                    + base[2 * 16384 + idx] + base[3 * 16384 + idx];
            a += v * v;
        }
        for (int off = 32; off; off >>= 1) a += __shfl_down(a, off);
        if ((t & 63) == 0) wsum[t >> 6] = a;
        __syncthreads();
        if (t == 0) {
            float w = (c_TM[tt] == c_TN[tt]) ? 1.0f : 2.0f;
            atomicAdd(&F[c_DIAGP[li]], w * (wsum[0] + wsum[1] + wsum[2] + wsum[3]));
        }
    } else {
        // ---- pair dots ----
        int p = b - 60, i = c_PI[p], j = c_PJ[p];
        const float invN = 1.0f / (float)NPTS;
        float dd = 0.f, rr = 0.f, sd = 0.f;
        for (int n = t; n < NPTS; n += 256) {
            float di = dv[i * NPTS + n], dj = dv[j * NPTS + n];
            float ri = (xs[i * NPTS + n] - di) * invN;
            float rj = (xs[j * NPTS + n] - dj) * invN;
            dd += di * dj;
            rr += ri * rj;
            sd += di;
        }
        red[t] = make_float4(dd, rr, sd, 0.f);
        __syncthreads();
        for (int h = 128; h > 0; h >>= 1) {
            if (t < h) {
                float4 a = red[t], bb = red[t + h];
                red[t] = make_float4(a.x + bb.x, a.y + bb.y, a.z + bb.z, 0.f);
            }
            __syncthreads();
        }
        if (t == 0) {
            atomicExch(&ddot[p], red[0].x);
            atomicExch(&rdot[p], red[0].y);
            if (i == j)
                atomicExch(&tb[i],
                    (tbss[i] - red[0].z) * (1.0f / ((float)NPTS * (float)NPTS)));
        }
    }

    // ---- last-block finalize (atomic counter; no spinning) ----
    __syncthreads();
    if (t == 0) {
        __threadfence();
        unsigned old = atomicAdd(cnt, 1u);
        lastFlag = (old == NTAIL - 1);
    }
    __syncthreads();
    if (!lastFlag) return;
    __threadfence();
    if (t < ML) tbv[t] = atomicAdd(&tb[t], 0.0f);
    __syncthreads();
    if (t < NPAIR) {
        int i = c_PI[t], j = c_PJ[t];
        double Fv = (double)atomicAdd(&F[t], 0.0f);
        double dd = (double)atomicAdd(&ddot[t], 0.0f);
        double rd = (double)atomicAdd(&rdot[t], 0.0f);
        double v = Fv - dd - 2.0 * (double)NPTS * rd
                 + (double)NPTS * (double)NPTS * (double)tbv[i] * (double)tbv[j];
        hs[i][j] = v; hs[j][i] = v;
    }
    __syncthreads();
    if (t < ML * ML) {
        int i = t / ML, j = t % ML;
        float v;
        if (i == j) v = 1.0f;
        else v = (float)(fabs(hs[i][j]) / sqrt(hs[i][i] * hs[j][j] + 1e-6));
        cka[i][j] = v;
        out[t] = v;
    }
    __syncthreads();
    if (t == 0) {
        float l = 0.f;
        for (int i = 1; i < ML; ++i)
            for (int j = 0; j < i; ++j) l += cka[i][j];   // cka >= 0
        out[ML * ML] = l;
    }
}

extern "C" void kernel_launch(void* const* d_in, const int* in_sizes, int n_in,
                              void* d_out, int out_size, void* d_ws, size_t ws_size,
                              hipStream_t stream) {
    (void)in_sizes; (void)n_in; (void)out_size; (void)ws_size;
    const float* X = (const float*)d_in[0];
    float* out = (float*)d_out;
    char* ws = (char*)d_ws;
    u8*    Xt8 = (u8*)(ws + OFF_XT8);
    float* CP  = (float*)(ws + OFF_CP);
    float* sp  = (float*)(ws + OFF_SP);
    float* dvp = (float*)(ws + OFF_DVP);
    float* F   = (float*)(ws + OFF_F);
    unsigned* cnt = (unsigned*)(ws + OFF_F + 256u);
    float* tbss = (float*)(ws + OFF_F + 512u);
    float* dv  = (float*)(ws + OFF_D);
    float* xs  = (float*)(ws + OFF_XS);
    float* dd  = (float*)(ws + OFF_DD);
    float* rd  = (float*)(ws + OFF_RD);
    float* tb  = (float*)(ws + OFF_T);

    hipLaunchKernelGGL(k_transpose, dim3(64, 8, 6), dim3(256), 0, stream,
                       X, Xt8, sp, dvp, F, cnt, tbss, dv, xs);
    hipLaunchKernelGGL(k_gemm_frob, dim3(NGEMMBLK + NSTATS), dim3(256), 0, stream,
                       Xt8, CP, F, sp, dvp, dv, xs, tbss);
    hipLaunchKernelGGL(k_tail, dim3(NTAIL), dim3(256), 0, stream,
                       CP, dv, xs, tbss, F, dd, rd, tb, cnt, out);
}